// Round 8
// baseline (43.104 us; speedup 1.0000x reference)
//
#include <hip/hip_runtime.h>
#include <cstdint>

typedef unsigned long long u64;
typedef unsigned int u32;

#define BB 64
#define DD 128
#define OO 512
#define II 512             // bytes per row (mode 0)
#define OT 64              // o-tile per block -> 1024 fused blocks
#define WPR 16             // packed u32 words per 512-elem row
#define XROWS (BB * DD)    // 8192 x rows; px = XROWS*16 u32 = 512 KB
#define LROW 17            // LDS row stride (17 coprime 32 -> <=2-way reads)

// ---------------------------------------------------------------------------
// Input-format detection. mode 0: bytes {0,1} | 1: int32 {0,1} | 2: f32 {0,1}
// Round-6/7 counters (cold FETCH 74MB << int32's 134MB compulsory) say bytes.
// ---------------------------------------------------------------------------
__device__ __forceinline__ int detect_mode(const u32* __restrict__ w) {
    bool all01 = true, allf = true;
#pragma unroll
    for (int i = 0; i < 32; ++i) {
        u32 v = w[i];
        all01 = all01 && (v <= 1u);
        allf  = allf  && (v == 0u || v == 0x3F800000u);
    }
    return all01 ? 1 : (allf ? 2 : 0);
}

// 4 bytes {0,1} (one LE u32) -> 4 bits. Bytes' high bits are 0, so the OR
// never contaminates: bit m of result = byte m's LSB.
__device__ __forceinline__ u32 nib4(u32 v) {
    return (v | (v >> 7) | (v >> 14) | (v >> 21)) & 0xFu;
}
// 32 bytes (two uint4, LE) -> one packed u32; bit j <-> byte j.
__device__ __forceinline__ u32 pack32_bytes(uint4 a, uint4 b) {
    return  nib4(a.x)        | (nib4(a.y) << 4)  | (nib4(a.z) << 8)  |
           (nib4(a.w) << 12) | (nib4(b.x) << 16) | (nib4(b.y) << 20) |
           (nib4(b.z) << 24) | (nib4(b.w) << 28);
}
// 32 u32 elements -> one packed u32 (mode 1: sh=0; mode 2: sh=23).
__device__ __forceinline__ u32 pack32_words(const u32* __restrict__ p, u32 sh) {
    u32 r = 0;
#pragma unroll
    for (int i = 0; i < 32; i += 4) {
        uint4 v = *(const uint4*)(p + i);
        r |= (((v.x >> sh) & 1u) << i)       | (((v.y >> sh) & 1u) << (i + 1)) |
             (((v.z >> sh) & 1u) << (i + 2)) | (((v.w >> sh) & 1u) << (i + 3));
    }
    return r;
}

// ---------------------------------------------------------------------------
// Kernel 1: pack x once into d_ws. Thread t packs word t: bytes [32t,32t+32)
// of the flat x byte stream (x row b*DD+d is flat row t>>4 -- natural order).
// Pure stream: loads 2KB-contiguous per wave-instr, stores 256B-contiguous.
// ---------------------------------------------------------------------------
__global__ __launch_bounds__(256)
void pack_x_kernel(const void* __restrict__ x, const void* __restrict__ w,
                   u32* __restrict__ px) {
    const int t = blockIdx.x * 256 + threadIdx.x;   // 0 .. XROWS*WPR-1
    const int mode = detect_mode((const u32*)w);
    u32 word;
    if (mode == 0) {
        const uint8_t* p = (const uint8_t*)x + (size_t)t * 32;
        uint4 a = *(const uint4*)p, b = *(const uint4*)(p + 16);
        word = pack32_bytes(a, b);
    } else {
        word = pack32_words((const u32*)x + (size_t)t * 32, mode == 1 ? 0u : 23u);
    }
    px[t] = word;
}

// ---------------------------------------------------------------------------
// Kernel 2 (fused GEMM): block = (d, 64-wide o-tile); 1024 blocks.
// Pack phase: thread t packs tile words [4t, 4t+4) of the 32KB-contiguous
// w tile -- 8 dwordx4 per thread, all issued before any pack ALU (per-thread
// ILP, no cross-lane ballot chain; this attacks round-7's VGPR=48 wall).
// px tile (4KB) is read from L2/L3 (written once by kernel 1).
// Phase C: thread owns o = tid&63, 16 b's:
//   matches = 512 - popcount(x ^ w); out = (matches > bias) as int32.
// ---------------------------------------------------------------------------
__global__ __launch_bounds__(256, 4)
void fused_kernel(const void* __restrict__ w, const u32* __restrict__ px,
                  const float* __restrict__ bias, int* __restrict__ out) {
    __shared__ u32 wpl[OT * LROW];   // stride 17: Phase-C reads <=2-way
    __shared__ u32 xpl[BB * LROW];   // Phase-C reads wave-uniform (broadcast)

    const int tid = threadIdx.x;
    const int bid = blockIdx.x;
    const int xcd = bid & 7;
    const int idx = bid >> 3;            // 0..127
    const int d   = xcd * 16 + (idx >> 3);
    const int o0  = (idx & 7) * OT;

    const int mode = detect_mode((const u32*)w);

    // ---- pack w tile: 1024 words, 4 per thread -------------------------
    if (mode == 0) {
        const uint8_t* tb = (const uint8_t*)w + (size_t)(d * OO + o0) * II
                          + (size_t)tid * 128;
        uint4 va[8];
#pragma unroll
        for (int i = 0; i < 8; ++i)              // 8 independent dwordx4
            va[i] = *(const uint4*)(tb + 16 * i);
#pragma unroll
        for (int i = 0; i < 4; ++i) {
            const int f = 4 * tid + i;           // tile word index
            wpl[(f >> 4) * LROW + (f & 15)] = pack32_bytes(va[2 * i], va[2 * i + 1]);
        }
    } else {
        const u32 sh = (mode == 1) ? 0u : 23u;
        const u32* tb = (const u32*)w + (size_t)(d * OO + o0) * II + (size_t)tid * 128;
#pragma unroll
        for (int i = 0; i < 4; ++i) {
            const int f = 4 * tid + i;
            wpl[(f >> 4) * LROW + (f & 15)] = pack32_words(tb + 32 * i, sh);
        }
    }
    // ---- fetch packed x tile: 1024 words from px (L2/L3-hot) -----------
#pragma unroll
    for (int j = 0; j < 4; ++j) {
        const int f = 256 * j + tid;             // b = f>>4, k = f&15
        const int b = f >> 4, k = f & 15;
        xpl[b * LROW + k] = px[((size_t)(b * DD + d) << 4) | k];
    }
    const float bv = bias[d * OO + o0 + (tid & 63)];
    __syncthreads();

    const int o  = tid & 63;
    const int b0 = (tid >> 6) * 16;

    u32 wr[WPR];
#pragma unroll
    for (int k = 0; k < WPR; ++k) wr[k] = wpl[o * LROW + k];

    int* outp = out + (size_t)d * OO + o0 + o;
#pragma unroll 4
    for (int bi = 0; bi < 16; ++bi) {
        const int b = b0 + bi;
        int m = 0;
#pragma unroll
        for (int k = 0; k < WPR; ++k) m += __popc(xpl[b * LROW + k] ^ wr[k]);
        const float act = (float)(512 - m);      // exact integer in fp32
        outp[(size_t)b * (DD * OO)] = (act > bv) ? 1 : 0;
    }
}

extern "C" void kernel_launch(void* const* d_in, const int* in_sizes, int n_in,
                              void* d_out, int out_size, void* d_ws, size_t ws_size,
                              hipStream_t stream) {
    const void*  x    = d_in[0];                 // (B, D, I) binary bytes
    const void*  w    = d_in[1];                 // (D, O, I) binary bytes
    const float* bias = (const float*)d_in[2];   // (D, O) f32
    int*         out  = (int*)d_out;             // (B, D, O) bool as int32
    u32*         px   = (u32*)d_ws;              // 512 KB packed x

    pack_x_kernel<<<XROWS * WPR / 256, 256, 0, stream>>>(x, w, px);
    fused_kernel<<<DD * (OO / OT), 256, 0, stream>>>(w, px, bias, out);
}

// Round 9
// 38.622 us; speedup vs baseline: 1.1161x; 1.1161x over previous
//
#include <hip/hip_runtime.h>
#include <cstdint>

typedef unsigned long long u64;
typedef unsigned int u32;

#define BB 64
#define DD 128
#define OO 512
#define II 512             // elements (bytes in mode 0) per row
#define OT 64              // o-tile per fused block -> 1024 blocks
#define XROWS (BB * DD)    // 8192 packed x rows; px = XROWS*64B = 512 KB

// ---------------------------------------------------------------------------
// Input-format detection. mode 0: bytes {0,1} | 1: int32 {0,1} | 2: f32 {0,1}
// Rounds 6-8 counters (cold FETCH 74MB << int32's 134MB compulsory) say the
// real data is mode 0 (bytes). Other modes kept for robustness.
// ---------------------------------------------------------------------------
__device__ __forceinline__ int detect_mode(const u32* __restrict__ w) {
    bool all01 = true, allf = true;
#pragma unroll
    for (int i = 0; i < 32; ++i) {
        u32 v = w[i];
        all01 = all01 && (v <= 1u);
        allf  = allf  && (v == 0u || v == 0x3F800000u);
    }
    return all01 ? 1 : (allf ? 2 : 0);
}

// 8 ballots pack one row's 512 bytes (lane holds bytes [8L,8L+8) as one LE
// u64) into 8 u64 words; lane j (j<8) keeps word j. Bijection (elem 8L+j ->
// word j bit L) is identical everywhere, so popcount(xor) is exact.
__device__ __forceinline__ u64 ballots8_bytes(u64 v, int lane) {
    u64 keep = 0;
#pragma unroll
    for (int j = 0; j < 8; ++j) {
        u64 bj = __ballot((u32)(v >> (8 * j)) & 1u);
        if (lane == j) keep = bj;
    }
    return keep;
}

// Generic row packer (global source), used by pack_x and the non-byte
// fallback. Lane-adjacent coalesced loads + 8 ballots.
__device__ __forceinline__ u64 pack_row(const void* __restrict__ src,
                                        size_t elem0, int mode, int lane) {
    u64 my = 0;
    if (mode == 0) {
        u64 v = *(const u64*)((const uint8_t*)src + elem0 + (size_t)lane * 8);
        my = ballots8_bytes(v, lane);
    } else {
        const u32 sh = (mode == 1) ? 0u : 23u;   // int32: bit0; float: bit23
        const uint4* p = (const uint4*)((const u32*)src + elem0);
        uint4 a = p[lane];         // elems [4L, 4L+4)
        uint4 b = p[64 + lane];    // elems [256+4L, ...)
        u64 w0 = __ballot((a.x >> sh) & 1u), w1 = __ballot((a.y >> sh) & 1u);
        u64 w2 = __ballot((a.z >> sh) & 1u), w3 = __ballot((a.w >> sh) & 1u);
        u64 w4 = __ballot((b.x >> sh) & 1u), w5 = __ballot((b.y >> sh) & 1u);
        u64 w6 = __ballot((b.z >> sh) & 1u), w7 = __ballot((b.w >> sh) & 1u);
        if (lane == 0) my = w0;  if (lane == 1) my = w1;
        if (lane == 2) my = w2;  if (lane == 3) my = w3;
        if (lane == 4) my = w4;  if (lane == 5) my = w5;
        if (lane == 6) my = w6;  if (lane == 7) my = w7;
    }
    return my;
}

// Async global->LDS DMA, 16B per lane (1KB per wave-instr). No dest VGPR ->
// the compiler's register-pressure load serialization (rounds 6-7 wall)
// doesn't apply; the vmcnt queue keeps all transfers in flight.
__device__ __forceinline__ void gload_lds16(const void* g, void* lds) {
    __builtin_amdgcn_global_load_lds(
        (const __attribute__((address_space(1))) void*)g,
        (__attribute__((address_space(3))) void*)lds, 16, 0, 0);
}

// ---------------------------------------------------------------------------
// Kernel 1: pack x once into d_ws (row-major u64[row][8], row = b*DD+d).
// One wave per row; fully-coalesced 512B loads.
// ---------------------------------------------------------------------------
__global__ __launch_bounds__(256)
void pack_x_kernel(const void* __restrict__ x, const void* __restrict__ w,
                   u64* __restrict__ px) {
    const int gtid = blockIdx.x * 256 + threadIdx.x;
    const int row  = gtid >> 6;          // 0..XROWS-1
    const int lane = threadIdx.x & 63;
    const int mode = detect_mode((const u32*)w);
    u64 my = pack_row(x, (size_t)row * II, mode, lane);
    if (lane < 8) px[(size_t)row * 8 + lane] = my;
}

// ---------------------------------------------------------------------------
// Kernel 2 (fused): block = (d, 64-wide o-tile); 1024 blocks, 4/CU exactly
// (LDS 24.7KB, launch_bounds(256,4)). XCD swizzle co-locates a d's o-tiles.
// mode 0 path: stage w tile in two 16KB halves via global_load_lds (DMA,
// deep pipeline), DMA the 4KB packed-x tile straight into xp's final layout,
// ballot-pack w from LDS. Phase C: thread owns o=tid&63 and 16 b's:
//   matches = 512 - popcount(x ^ w); out = (matches > bias) as int32.
// ---------------------------------------------------------------------------
__global__ __launch_bounds__(256, 4)
void fused_kernel(const void* __restrict__ x, const void* __restrict__ w,
                  const u64* __restrict__ px,
                  const float* __restrict__ bias, int* __restrict__ out) {
    __shared__ u64 stage64[2048];        // 16KB raw w staging (half tile)
    __shared__ u64 wp[OT][9];            // +1 pad: Phase-C read <=4-way
    __shared__ u64 xp[BB][8];            // linear == px row layout

    const int tid  = threadIdx.x;
    const int bid  = blockIdx.x;
    const int xcd  = bid & 7;
    const int idx  = bid >> 3;           // 0..127
    const int d    = xcd * 16 + (idx >> 3);
    const int o0   = (idx & 7) * OT;
    const int wv   = tid >> 6;
    const int lane = tid & 63;

    const int mode = detect_mode((const u32*)w);
    const float bv = bias[d * OO + o0 + (tid & 63)];

    uint8_t* stage = (uint8_t*)stage64;

    if (mode == 0) {
        const uint8_t* wtile = (const uint8_t*)w + (size_t)(d * OO + o0) * II;

        // ---- stage phase 0: w rows 0-31 (16 instrs, 4/wave) + x tile ----
#pragma unroll
        for (int i = 0; i < 4; ++i) {
            const int inst = wv * 4 + i;
            gload_lds16(wtile + inst * 1024 + lane * 16, stage + inst * 1024);
        }
        {   // x: 4KB, instr wv; lane L -> row b = wv*16+(L>>2), 16B chunk L&3
            const int b = wv * 16 + (lane >> 2);
            gload_lds16((const uint8_t*)px + ((size_t)(b * DD + d)) * 64
                                           + (size_t)(lane & 3) * 16,
                        (uint8_t*)xp + wv * 1024);
        }
        asm volatile("s_waitcnt vmcnt(0)" ::: "memory");
        __syncthreads();

        // ---- pack w rows 0-31 from LDS (ds_read_b64, <=4-way) ----
#pragma unroll
        for (int r = 0; r < 8; ++r) {
            const int row = wv * 8 + r;
            u64 v = *(const u64*)(stage + row * 512 + lane * 8);
            u64 k = ballots8_bytes(v, lane);
            if (lane < 8) wp[row][lane] = k;
        }
        __syncthreads();   // all stage reads done before overwrite

        // ---- stage phase 1: w rows 32-63 ----
#pragma unroll
        for (int i = 0; i < 4; ++i) {
            const int inst = wv * 4 + i;
            gload_lds16(wtile + 16384 + inst * 1024 + lane * 16,
                        stage + inst * 1024);
        }
        asm volatile("s_waitcnt vmcnt(0)" ::: "memory");
        __syncthreads();
#pragma unroll
        for (int r = 0; r < 8; ++r) {
            const int row = wv * 8 + r;
            u64 v = *(const u64*)(stage + row * 512 + lane * 8);
            u64 k = ballots8_bytes(v, lane);
            if (lane < 8) wp[32 + row][lane] = k;
        }
        __syncthreads();
    } else {
        // Fallback (int32/f32 data): ballot-pack w from global, xp from px.
#pragma unroll
        for (int r = 0; r < 16; ++r) {
            const int o = wv * 16 + r;
            u64 my = pack_row(w, ((size_t)(d * OO + o0 + o)) * II, mode, lane);
            if (lane < 8) wp[o][lane] = my;
        }
        for (int t = tid; t < BB * 8; t += 256) {
            const int b = t >> 3, k = t & 7;
            xp[b][k] = px[((size_t)(b * DD + d)) * 8 + k];
        }
        __syncthreads();
    }

    // ---- Phase C ----
    const int o  = tid & 63;
    const int b0 = (tid >> 6) * 16;

    u64 wr[8];
#pragma unroll
    for (int k = 0; k < 8; ++k) wr[k] = wp[o][k];

    int* outp = out + (size_t)d * OO + o0 + o;
#pragma unroll 4
    for (int bi = 0; bi < 16; ++bi) {
        const int b = b0 + bi;
        int m = 0;
#pragma unroll
        for (int k = 0; k < 8; ++k) m += __popcll(xp[b][k] ^ wr[k]);
        const float act = (float)(512 - m);   // exact integer in fp32
        outp[(size_t)b * (DD * OO)] = (act > bv) ? 1 : 0;
    }
}

extern "C" void kernel_launch(void* const* d_in, const int* in_sizes, int n_in,
                              void* d_out, int out_size, void* d_ws, size_t ws_size,
                              hipStream_t stream) {
    const void*  x    = d_in[0];                 // (B, D, I) binary bytes
    const void*  w    = d_in[1];                 // (D, O, I) binary bytes
    const float* bias = (const float*)d_in[2];   // (D, O) f32
    int*         out  = (int*)d_out;             // (B, D, O) bool as int32
    u64*         px   = (u64*)d_ws;              // 512 KB packed x

    pack_x_kernel<<<XROWS / 4, 256, 0, stream>>>(x, w, px);
    fused_kernel<<<DD * (OO / OT), 256, 0, stream>>>(x, w, px, bias, out);
}